// Round 1
// baseline (346.401 us; speedup 1.0000x reference)
//
#include <hip/hip_runtime.h>
#include <math.h>

typedef unsigned u32;
typedef _Float16 f16x8 __attribute__((ext_vector_type(8)));
typedef float    f32x16 __attribute__((ext_vector_type(16)));

static __device__ __forceinline__ u32 pack2(_Float16 a, _Float16 b) {
    union { _Float16 h[2]; u32 u; } v;
    v.h[0] = a; v.h[1] = b;
    return v.u;
}

// ws (halves): h1 13,271,040 | A1 129,024 | A2 576,000 | part 8,294,400 | h2 1,658,880
// total 23,929,344 h = 47.9 MB

// ---------------- A-pack: A1[se9][k2 28][lane64][j8] ----------------
__global__ __launch_bounds__(256) void pack_A1v2(
    const float* __restrict__ w1, _Float16* __restrict__ A1)
{
    int i = blockIdx.x * 256 + threadIdx.x;      // 129024 exact
    int j = i & 7;
    int lane = (i >> 3) & 63;
    int t = i >> 9;
    int k2 = t % 28;
    int se = t / 28;                             // 0..8
    int g = lane >> 5, m = lane & 31;
    int tap = 2 * k2 + g;                        // 0..55
    int we = tap / 7, kd = tap % 7;
    float v = 0.f;
    if (m < 30 && j < 7) {
        int dw = m / 15, dh = (m % 15) / 5, oc = m % 5;
        int kh = se - dh, kw = we - dw;
        if (kh >= 0 && kh < 7 && kw >= 0 && kw < 7)
            v = w1[oc * 2401 + kh * 343 + kw * 49 + kd * 7 + j];
    }
    A1[i] = (_Float16)v;
}

// ---------------- A-pack: A2[ci5][she9][k2 25][lane64][j8] ----------------
__global__ __launch_bounds__(256) void pack_A2v2(
    const float* __restrict__ w2, _Float16* __restrict__ A2)
{
    int i = blockIdx.x * 256 + threadIdx.x;      // 576000 exact
    int j = i & 7;
    int lane = (i >> 3) & 63;
    int t = i >> 9;
    int k2 = t % 25; t /= 25;
    int she = t % 9;
    int ci = t / 9;                              // 0..4
    int g = lane >> 5, m = lane & 31;
    int tap = 2 * k2 + g;                        // 0..49
    float v = 0.f;
    if (m < 30 && tap < 49 && j < 7) {
        int dh = m / 10, oc = m % 10;
        int kh = she - dh;
        if (kh >= 0 && kh < 7) {
            int kw = tap / 7, kd = tap % 7;
            v = w2[oc * 12005 + ci * 2401 + kh * 343 + kw * 49 + kd * 7 + j];
        }
    }
    A2[i] = (_Float16)v;
}

// ---------------- conv1: 32x32x16 MFMA, windowed LDS, 4 waves ----------------
// block=(b,OH,OWp): M=30=(dw2,dh3,oc5), N=288=(u2,od12,ot12) -> 9 nt,
// K = 9 se x 28 k2(2 taps x kt8).
// x-slab only in LDS: 180 rows x 64 dw, XOR bank swizzle ot*4 ^ ((row&7)<<2).
// A fragments straight from global (L1-resident 28KB/se) via depth-4 rolling regs.
#define C1_STRIDE 64
#define C1_ROWS 180
__global__ __launch_bounds__(256, 3) void conv1_mfma(
    const float* __restrict__ x, const _Float16* __restrict__ A1,
    const float* __restrict__ b1, _Float16* __restrict__ h1)
{
    __shared__ u32 lds[C1_ROWS * C1_STRIDE];     // 46.1 KB
    int tid = threadIdx.x;
    int lane = tid & 63;
    int wave = tid >> 6;
    int col = lane & 31;
    int g = lane >> 5;

    int bid = (int)blockIdx.x;                   // 1536 = 8*192
    int lbid = (bid & 7) * 192 + (bid >> 3);     // XCD chunk swizzle
    int OWp = lbid % 3;
    int OH = (lbid / 3) & 3;
    int b = lbid / 12;

    int qrow[3], qot[3], u_[3], od_[3], ot_[3];
    #pragma unroll
    for (int s = 0; s < 3; ++s) {
        int nt = wave + 4 * s;
        int n = (nt <= 8) ? nt * 32 + col : col;
        int u = n / 144, r2 = n % 144;
        int od = r2 / 12, ot = r2 % 12;
        u_[s] = u; od_[s] = od; ot_[s] = ot;
        qrow[s] = u * 36 + od;                   // + (we*18+kd) at use
        qot[s] = ot * 4;
    }

    f32x16 acc0, acc1, acc2;
    #pragma unroll
    for (int q = 0; q < 16; ++q) { acc0[q] = 0.f; acc1[q] = 0.f; acc2[q] = 0.f; }

    const float* xbase = x + (size_t)b * 104976;
    const uint4* a1u = (const uint4*)A1;
    int w10 = tid / 18, id18 = tid % 18;
    int iw = 4 * OWp + w10;
    bool stager = (tid < 180);

    float2 xr[9];
    uint4 areg[4];                               // rolling A prefetch, slot = k2&3
    {   // preload x(se=0) and A(se=0, k2=0..3)
        if (stager) {
            const float2* src = (const float2*)(xbase + (3 * OH) * 5832 + iw * 324 + id18 * 18);
            #pragma unroll
            for (int q = 0; q < 9; ++q) xr[q] = src[q];
        }
        #pragma unroll
        for (int i = 0; i < 4; ++i) areg[i] = a1u[i * 64 + lane];
    }

    for (int se = 0; se < 9; ++se) {
        const uint4* apc = a1u + (size_t)se * 1792;
        const uint4* apn = a1u + (size_t)(se < 8 ? se + 1 : 8) * 1792;
        __syncthreads();                         // prior compute done
        if (stager) {
            _Float16 h[19];
            #pragma unroll
            for (int q = 0; q < 9; ++q) { h[2*q] = (_Float16)xr[q].x; h[2*q+1] = (_Float16)xr[q].y; }
            h[18] = (_Float16)0.f;
            u32 e[9], o[9];
            #pragma unroll
            for (int q = 0; q < 9; ++q) e[q] = pack2(h[2*q], h[2*q+1]);
            #pragma unroll
            for (int q = 0; q < 9; ++q) o[q] = pack2(h[2*q+1], (q < 8) ? h[2*q+2] : h[18]);
            int base = tid * C1_STRIDE;
            int swz = (tid & 7) << 2;
            #pragma unroll
            for (int ot = 0; ot < 12; ++ot) {
                uint4 w;
                if ((ot & 1) == 0) { const int q = ot >> 1;   w = (uint4){e[q], e[q+1], e[q+2], e[q+3]}; }
                else               { const int q = (ot-1)>>1; w = (uint4){o[q], o[q+1], o[q+2], o[q+3]}; }
                *(uint4*)(&lds[base + ((ot * 4) ^ swz)]) = w;
            }
        }
        __syncthreads();

        if (se < 8 && stager) {                  // prefetch next x stage into regs
            const float2* src = (const float2*)(xbase + (3 * OH + se + 1) * 5832 + iw * 324 + id18 * 18);
            #pragma unroll
            for (int q = 0; q < 9; ++q) xr[q] = src[q];
        }

        #pragma unroll
        for (int k2 = 0; k2 < 28; ++k2) {
            const int t0 = 2 * k2, t1 = 2 * k2 + 1;
            const int c0r = (t0 / 7) * 18 + (t0 % 7);
            const int c1r = (t1 / 7) * 18 + (t1 % 7);
            f16x8 af = *(const f16x8*)&areg[k2 & 3];
            {   // rolling prefetch: k2+4 of this se, or k2-24 of next se
                const int nk = k2 + 4;
                areg[k2 & 3] = (nk < 28) ? apc[nk * 64 + lane]
                                         : apn[(nk - 28) * 64 + lane];
            }
            int crow = g ? c1r : c0r;
            int r0 = qrow[0] + crow;
            int r1 = qrow[1] + crow;
            f16x8 bf0 = *(const f16x8*)(lds + r0 * C1_STRIDE + (qot[0] ^ ((r0 & 7) << 2)));
            f16x8 bf1 = *(const f16x8*)(lds + r1 * C1_STRIDE + (qot[1] ^ ((r1 & 7) << 2)));
            acc0 = __builtin_amdgcn_mfma_f32_32x32x16_f16(af, bf0, acc0, 0, 0, 0);
            acc1 = __builtin_amdgcn_mfma_f32_32x32x16_f16(af, bf1, acc1, 0, 0, 0);
            if (wave == 0) {
                int rr = qrow[2] + crow;
                f16x8 bf2 = *(const f16x8*)(lds + rr * C1_STRIDE + (qot[2] ^ ((rr & 7) << 2)));
                acc2 = __builtin_amdgcn_mfma_f32_32x32x16_f16(af, bf2, acc2, 0, 0, 0);
            }
        }
    }

    // store: C row = (r&3)+8*(r>>2)+4*g -> m = dw*15+dh*5+oc; col -> (u,od,ot)
    #pragma unroll
    for (int s = 0; s < 3; ++s) {
        if (s == 2 && wave != 0) continue;
        f32x16 a = (s == 0) ? acc0 : ((s == 1) ? acc1 : acc2);
        int ow_b = 4 * OWp + 2 * u_[s];
        #pragma unroll
        for (int r = 0; r < 16; ++r) {
            const int m0 = (r & 3) + 8 * (r >> 2);
            const int m1 = m0 + 4;
            const int dw0 = m0 / 15, dh0 = (m0 % 15) / 5, oc0 = m0 % 5;
            const int dw1 = m1 / 15, dh1 = (m1 % 15) / 5, oc1 = m1 % 5;
            if (m1 >= 30 && g) continue;
            int dw = g ? dw1 : dw0;
            int dh = g ? dh1 : dh0;
            int oc = g ? oc1 : oc0;
            float bv = g ? b1[oc1] : b1[oc0];
            float v = fmaxf(a[r] + bv, 0.f);
            h1[(size_t)b * 103680 + oc * 20736 + (3 * OH + dh) * 1728
               + (ow_b + dw) * 144 + od_[s] * 12 + ot_[s]] = (_Float16)v;
        }
    }
}

// ---------------- conv2: 32x32x16 MFMA, windowed LDS, ci-split ----------------
// block=(b,OH2,ci): M=30=(dh3,oc10), N=216 -> 7 nt, K = 9 she x 25 k2.
// x-slab only in LDS: 144 rows x 32 dw, XOR swizzle. A via depth-5 rolling regs.
#define C2_STRIDE 32
#define C2_ROWS 144
__global__ __launch_bounds__(256, 4) void conv2_mfma(
    const _Float16* __restrict__ h1, const _Float16* __restrict__ A2,
    _Float16* __restrict__ part)
{
    __shared__ u32 lds[C2_ROWS * C2_STRIDE];     // 18.4 KB
    int tid = threadIdx.x;
    int lane = tid & 63;
    int wave = tid >> 6;
    int col = lane & 31;
    int g = lane >> 5;

    int bid = (int)blockIdx.x;                   // 1280 = 8*160
    int lbid = (bid & 7) * 160 + (bid >> 3);
    int ci = lbid % 5;
    int OH2 = (lbid / 5) & 1;
    int b = lbid / 10;

    int qrow[2], qot[2], n_[2];
    #pragma unroll
    for (int s = 0; s < 2; ++s) {
        int nt = wave + 4 * s;
        int n = nt * 32 + col;                   // nt<=6 -> n<224
        n_[s] = n;
        int nc = (n < 216) ? n : 215;
        int ow = nc / 36, rem = nc % 36;
        int od = rem / 6, ot = rem % 6;
        qrow[s] = ow * 12 + od;
        qot[s] = ot * 4;
    }

    f32x16 acc0, acc1;
    #pragma unroll
    for (int q = 0; q < 16; ++q) { acc0[q] = 0.f; acc1[q] = 0.f; }

    const _Float16* hbase = h1 + (size_t)b * 103680 + ci * 20736;
    const uint4* a2u = (const uint4*)(A2 + ((size_t)ci * 9) * 12800);
    int iw = tid / 12, id12 = tid % 12;
    bool stager = (tid < 144);

    uint2 xr[3];
    uint4 areg[5];                               // rolling A prefetch, slot = k2%5
    {
        if (stager) {
            const uint2* src = (const uint2*)(hbase + (3 * OH2) * 1728 + iw * 144 + id12 * 12);
            #pragma unroll
            for (int q = 0; q < 3; ++q) xr[q] = src[q];
        }
        #pragma unroll
        for (int i = 0; i < 5; ++i) areg[i] = a2u[i * 64 + lane];
    }

    for (int she = 0; she < 9; ++she) {
        const uint4* apc = a2u + (size_t)she * 1600;
        const uint4* apn = a2u + (size_t)(she < 8 ? she + 1 : 8) * 1600;
        __syncthreads();
        if (stager) {
            _Float16 h[14];
            *(uint2*)&h[0] = xr[0]; *(uint2*)&h[4] = xr[1]; *(uint2*)&h[8] = xr[2];
            h[12] = (_Float16)0.f;
            u32 e[6], o[6];
            #pragma unroll
            for (int q = 0; q < 6; ++q) e[q] = pack2(h[2*q], h[2*q+1]);
            #pragma unroll
            for (int q = 0; q < 6; ++q) o[q] = pack2(h[2*q+1], (q < 5) ? h[2*q+2] : h[12]);
            int base = tid * C2_STRIDE;
            int swz = (tid & 7) << 2;
            #pragma unroll
            for (int ot = 0; ot < 6; ++ot) {
                uint4 w;
                if ((ot & 1) == 0) { const int q = ot >> 1;   w = (uint4){e[q], e[q+1], e[q+2], e[q+3]}; }
                else               { const int q = (ot-1)>>1; w = (uint4){o[q], o[q+1], o[q+2], o[q+3]}; }
                *(uint4*)(&lds[base + ((ot * 4) ^ swz)]) = w;
            }
        }
        __syncthreads();

        if (she < 8 && stager) {
            const uint2* src = (const uint2*)(hbase + (3 * OH2 + she + 1) * 1728 + iw * 144 + id12 * 12);
            #pragma unroll
            for (int q = 0; q < 3; ++q) xr[q] = src[q];
        }

        #pragma unroll
        for (int k2 = 0; k2 < 25; ++k2) {
            const int t0 = 2 * k2, t1 = 2 * k2 + 1;
            const int c0r = (t0 / 7) * 12 + (t0 % 7);
            const int c1r = (t1 < 49) ? ((t1 / 7) * 12 + (t1 % 7)) : 0;
            f16x8 af = *(const f16x8*)&areg[k2 % 5];
            {   // rolling prefetch: k2+5 of this she, or k2-20 of next she
                const int nk = k2 + 5;
                areg[k2 % 5] = (nk < 25) ? apc[nk * 64 + lane]
                                         : apn[(nk - 25) * 64 + lane];
            }
            int crow = g ? c1r : c0r;
            int r0 = qrow[0] + crow;
            f16x8 bf0 = *(const f16x8*)(lds + r0 * C2_STRIDE + (qot[0] ^ ((r0 & 7) << 2)));
            acc0 = __builtin_amdgcn_mfma_f32_32x32x16_f16(af, bf0, acc0, 0, 0, 0);
            if (wave < 3) {
                int r1 = qrow[1] + crow;
                f16x8 bf1 = *(const f16x8*)(lds + r1 * C2_STRIDE + (qot[1] ^ ((r1 & 7) << 2)));
                acc1 = __builtin_amdgcn_mfma_f32_32x32x16_f16(af, bf1, acc1, 0, 0, 0);
            }
        }
    }

    // store partials: part[ci][b*6+oh][oc][216]; m = dh*10+oc
    #pragma unroll
    for (int s = 0; s < 2; ++s) {
        if (s == 1 && wave >= 3) continue;
        if (n_[s] >= 216) continue;
        f32x16 a = (s == 0) ? acc0 : acc1;
        #pragma unroll
        for (int r = 0; r < 16; ++r) {
            const int m0 = (r & 3) + 8 * (r >> 2);
            const int m1 = m0 + 4;
            const int dh0 = m0 / 10, oc0 = m0 % 10;
            const int dh1 = m1 / 10, oc1 = m1 % 10;
            if (m1 >= 30 && g) continue;
            int dh = g ? dh1 : dh0;
            int oc = g ? oc1 : oc0;
            int oh = 3 * OH2 + dh;
            part[((size_t)(ci * 768 + b * 6 + oh) * 10 + oc) * 216 + n_[s]] = (_Float16)a[r];
        }
    }
}

// ---------------- reduce 5 ci-partials + bias + ReLU -> h2 ----------------
__global__ __launch_bounds__(256) void conv2_reduce(
    const _Float16* __restrict__ part, const float* __restrict__ b2,
    _Float16* __restrict__ h2)
{
    int flat = blockIdx.x * 256 + threadIdx.x;   // 1,658,880 exact
    int n_loc = flat % 216;
    int t = flat / 216;
    int oc = t % 10;  t /= 10;
    int oh = t % 6;
    int b  = t / 6;
    float s = 0.f;
    #pragma unroll
    for (int ci = 0; ci < 5; ++ci)
        s += (float)part[((size_t)(ci * 768 + b * 6 + oh) * 10 + oc) * 216 + n_loc];
    s = fmaxf(s + b2[oc], 0.f);
    h2[(size_t)b * 12960 + oc * 1296 + oh * 216 + n_loc] = (_Float16)s;
}

// ---------------- linear + sigmoid ----------------
__global__ __launch_bounds__(256) void linear_kernel(
    const _Float16* __restrict__ h2, const float* __restrict__ wl,
    const float* __restrict__ bl, float* __restrict__ out)
{
    int b = blockIdx.x;
    const _Float16* hb = h2 + (size_t)b * 12960;
    float s = 0.f;
    for (int i = threadIdx.x; i < 12960; i += 256)
        s += (float)hb[i] * wl[i];
    #pragma unroll
    for (int off = 32; off > 0; off >>= 1)
        s += __shfl_down(s, off, 64);
    __shared__ float wsum[4];
    int wave = threadIdx.x >> 6;
    if ((threadIdx.x & 63) == 0) wsum[wave] = s;
    __syncthreads();
    if (threadIdx.x == 0) {
        float tot = wsum[0] + wsum[1] + wsum[2] + wsum[3] + bl[0];
        out[b] = 1.f / (1.f + expf(-tot));
    }
}

extern "C" void kernel_launch(void* const* d_in, const int* in_sizes, int n_in,
                              void* d_out, int out_size, void* d_ws, size_t ws_size,
                              hipStream_t stream) {
    const float* x  = (const float*)d_in[0];
    const float* w1 = (const float*)d_in[1];
    const float* b1 = (const float*)d_in[2];
    const float* w2 = (const float*)d_in[3];
    const float* b2 = (const float*)d_in[4];
    const float* wl = (const float*)d_in[5];
    const float* bl = (const float*)d_in[6];
    float* out = (float*)d_out;

    _Float16* h1   = (_Float16*)d_ws;            // 13,271,040
    _Float16* A1   = h1 + 13271040;              //    129,024
    _Float16* A2   = A1 + 129024;                //    576,000
    _Float16* part = A2 + 576000;                //  8,294,400
    _Float16* h2   = part + 8294400;             //  1,658,880

    pack_A1v2<<<504, 256, 0, stream>>>(w1, A1);
    pack_A2v2<<<2250, 256, 0, stream>>>(w2, A2);
    conv1_mfma<<<1536, 256, 0, stream>>>(x, A1, b1, h1);
    conv2_mfma<<<1280, 256, 0, stream>>>(h1, A2, part);
    conv2_reduce<<<6480, 256, 0, stream>>>(part, b2, h2);
    linear_kernel<<<128, 256, 0, stream>>>(h2, wl, bl, out);
}